// Round 12
// baseline (271.697 us; speedup 1.0000x reference)
//
#include <hip/hip_runtime.h>
#include <math.h>

#define EPSV 1e-5f

typedef __attribute__((ext_vector_type(8))) short short8;
typedef __attribute__((ext_vector_type(8))) unsigned short ushort8;
typedef __attribute__((ext_vector_type(4))) float f32x4;

__device__ __forceinline__ unsigned short f2bf(float f){
  unsigned u = __builtin_bit_cast(unsigned, f);
  u += 0x7fffu + ((u >> 16) & 1u);            // RNE to bf16
  return (unsigned short)(u >> 16);
}
__device__ __forceinline__ float dot4f(float4 w, const float* v){
  return w.x*v[0] + w.y*v[1] + w.z*v[2] + w.w*v[3];
}
__device__ __forceinline__ float sigmoidf(float v){ return 1.f/(1.f + expf(-v)); }

// ---------------------------------------------------------------------------
// Pack weights into MFMA B-fragment-linear bf16.
__global__ __launch_bounds__(256) void k_pack(const float* __restrict__ w1,
                                              const float* __restrict__ wattn,
                                              unsigned short* __restrict__ p1,
                                              unsigned short* __restrict__ pkv){
  const int total1 = 256*256, total2 = 1024*512;
  for (int idx = blockIdx.x*256 + threadIdx.x; idx < total1 + total2; idx += gridDim.x*256){
    if (idx < total1){
      int o = idx >> 8, c = idx & 255;
      int off = (((o>>4)*8 + (c>>5))*64 + (((c>>3)&3)*16 + (o&15)))*8 + (c&7);
      p1[off] = f2bf(w1[idx]);
    } else {
      int j = idx - total1; int o = j >> 9, c = j & 511;
      int off = (((o>>4)*16 + (c>>5))*64 + (((c>>3)&3)*16 + (o&15)))*8 + (c&7);
      pkv[off] = f2bf(wattn[512*512 + j]);
    }
  }
}

// ---------------------------------------------------------------------------
// K1: 1x1 conv (bf16 MFMA) + BN + ReLU + partial avg-pool + channel stats.
// R3 structure + NT x loads. Measured floor ~73 us (5 structural variants
// all equal); accepted as the x-pass floor.
__global__ __launch_bounds__(256) void k_conv(
    const float* __restrict__ x, const unsigned short* __restrict__ wp,
    const float* __restrict__ cb, const float* __restrict__ bng,
    const float* __restrict__ bnb, const float* __restrict__ bnm,
    const float* __restrict__ bnv,
    float* __restrict__ ppool, float* __restrict__ wavg, float* __restrict__ wmax){
  int bid = blockIdx.x;
  int b = bid >> 6, tile = bid & 63;
  int px0 = tile << 6;
  int t = threadIdx.x;
  int lane = t & 63, wv = t >> 6;
  int px = t & 63, cg = wv;
  __shared__ __align__(16) unsigned short a_lds[16384];
  __shared__ float st_s[256], st_m[256];

  const float* xb = x + (size_t)b*(256*4096) + px0 + px;

  float ssum = 0.f, smax = -3.4e38f;
  const unsigned wbase = (((px >> 4) << 6) + ((unsigned)cg << 4) + (px & 15)) << 4;

  #pragma unroll
  for (int ch = 0; ch < 8; ++ch){
    float xv[8];
    #pragma unroll
    for (int u = 0; u < 8; ++u)
      xv[u] = __builtin_nontemporal_load(xb + (size_t)(ch*32 + cg*8 + u) * 4096);
    ushort8 pk;
    #pragma unroll
    for (int u = 0; u < 8; ++u){
      ssum += xv[u];
      smax = fmaxf(smax, xv[u]);
      pk[u] = f2bf(xv[u]);
    }
    *(ushort8*)((char*)a_lds + wbase + (ch << 12)) = pk;
  }
  st_s[t] = ssum; st_m[t] = smax;
  __syncthreads();

  if (t < 64){
    float s = st_s[t] + st_s[t+64] + st_s[t+128] + st_s[t+192];
    float m = fmaxf(fmaxf(st_m[t], st_m[t+64]), fmaxf(st_m[t+128], st_m[t+192]));
    wavg[(b << 12) + px0 + t] = s * (1.f/256.f);
    wmax[(b << 12) + px0 + t] = m;
  }

  f32x4 acc[4][4];
  #pragma unroll
  for (int i = 0; i < 4; ++i)
    #pragma unroll
    for (int j = 0; j < 4; ++j){ f32x4 z = {0.f,0.f,0.f,0.f}; acc[i][j] = z; }

  #pragma unroll
  for (int ch = 0; ch < 8; ++ch){
    short8 afr[4];
    #pragma unroll
    for (int mf = 0; mf < 4; ++mf)
      afr[mf] = *(const short8*)((const char*)a_lds + (ch << 12) + (mf << 10) + lane*16);
    #pragma unroll
    for (int nf = 0; nf < 4; ++nf){
      short8 bfr = *(const short8*)(wp + (size_t)(((wv*4 + nf)*8 + ch) * 512 + lane*8));
      #pragma unroll
      for (int mf = 0; mf < 4; ++mf)
        acc[mf][nf] = __builtin_amdgcn_mfma_f32_16x16x32_bf16(afr[mf], bfr, acc[mf][nf], 0, 0, 0);
    }
  }

  #pragma unroll
  for (int nf = 0; nf < 4; ++nf){
    int o = (wv << 6) + (nf << 4) + (lane & 15);
    float sc = bng[o] * rsqrtf(bnv[o] + EPSV);
    float sh = bnb[o] + (cb[o] - bnm[o]) * sc;
    float ps = 0.f;
    #pragma unroll
    for (int mf = 0; mf < 4; ++mf)
      #pragma unroll
      for (int r = 0; r < 4; ++r)
        ps += fmaxf(acc[mf][nf][r] * sc + sh, 0.f);
    ps += __shfl_xor(ps, 16, 64);
    ps += __shfl_xor(ps, 32, 64);
    if ((lane & 48) == 0)
      ppool[(size_t)((b << 6) + tile)*256 + o] = ps;
  }
}

// ---------------------------------------------------------------------------
// K3: K/V projection of memory bank. Barrier-free, fragments direct from mb.
__global__ __launch_bounds__(256) void k_kv(const float* __restrict__ mb,
    const unsigned short* __restrict__ wp, const float* __restrict__ attb,
    float* __restrict__ kvb){
  int bid = blockIdx.x;
  int mt = bid >> 4, nt = bid & 15;
  int m0 = mt << 4;
  int mu = nt >> 3;
  int ncol0 = (nt & 7) << 6;
  int t = threadIdx.x, lane = t & 63, wv = t >> 6;
  int l15 = lane & 15, l4 = lane >> 4;

  const float* arow = mb + (size_t)(m0 + l15)*512 + l4*8;
  int ofrag = (nt << 2) + wv;

  f32x4 acc = {0.f,0.f,0.f,0.f};
  #pragma unroll
  for (int ch = 0; ch < 16; ++ch){
    float4 a0 = *(const float4*)(arow + ch*32);
    float4 a1 = *(const float4*)(arow + ch*32 + 4);
    short8 afr;
    afr[0] = (short)f2bf(a0.x); afr[1] = (short)f2bf(a0.y);
    afr[2] = (short)f2bf(a0.z); afr[3] = (short)f2bf(a0.w);
    afr[4] = (short)f2bf(a1.x); afr[5] = (short)f2bf(a1.y);
    afr[6] = (short)f2bf(a1.z); afr[7] = (short)f2bf(a1.w);
    short8 bfr = *(const short8*)(wp + (size_t)(ofrag*16 + ch)*512 + lane*8);
    acc = __builtin_amdgcn_mfma_f32_16x16x32_bf16(afr, bfr, acc, 0, 0, 0);
  }
  float bias = attb[512 + mu*512 + ncol0 + (wv << 4) + l15];
  #pragma unroll
  for (int i = 0; i < 4; ++i){
    int row = m0 + l4*4 + i;
    int col = ncol0 + (wv << 4) + l15;
    kvb[(size_t)mu*131072 + (size_t)row*512 + col] = acc[i] + bias;
  }
}

// ---------------------------------------------------------------------------
// K4a: per (b,head): ENC (recomputed from ppool, 8x redundant but cheap),
// q-proj, scores, softmax, ctx. grid = 32*8 = 256 blocks. Removes the k_enc
// launch + the enc global round-trip.
__global__ __launch_bounds__(256) void k_qkattn(const float* __restrict__ pp,
    const float* __restrict__ lw, const float* __restrict__ lb,
    const float* __restrict__ lng, const float* __restrict__ lnb,
    const float* __restrict__ kvb, const float* __restrict__ attw,
    const float* __restrict__ attb, float* __restrict__ ctxout){
  int bid = blockIdx.x;
  int b = bid >> 3, h = bid & 7;
  int t = threadIdx.x;
  __shared__ __align__(16) float p_s[256];
  __shared__ float e_s[512];
  __shared__ __align__(16) float q_s[64];
  __shared__ float att_s[256];
  __shared__ float red_s[256];
  __shared__ float r2[8];

  // ---- enc: pool + linear + LayerNorm (identical arithmetic to old k_enc) ----
  {
    float s = 0.f;
    for (int tile = 0; tile < 64; ++tile) s += pp[(size_t)((b<<6)+tile)*256 + t];
    p_s[t] = s * (1.f/4096.f);
  }
  __syncthreads();
  {
    float hv[2];
    #pragma unroll
    for (int k = 0; k < 2; ++k){
      int d = t + k*256;
      const float4* wr = (const float4*)(lw + (size_t)d*256);
      float a = 0.f;
      for (int j = 0; j < 64; ++j) a += dot4f(wr[j], &p_s[4*j]);
      hv[k] = a + lb[d];
    }
    float ls = hv[0] + hv[1], lq = hv[0]*hv[0] + hv[1]*hv[1];
    #pragma unroll
    for (int msk = 1; msk < 64; msk <<= 1){
      ls += __shfl_xor(ls, msk, 64);
      lq += __shfl_xor(lq, msk, 64);
    }
    if ((t & 63) == 0){ r2[t>>6] = ls; r2[4 + (t>>6)] = lq; }
    __syncthreads();
    float su = r2[0]+r2[1]+r2[2]+r2[3];
    float sq = r2[4]+r2[5]+r2[6]+r2[7];
    float mu = su * (1.f/512.f);
    float vr = sq * (1.f/512.f) - mu*mu;
    float rstd = rsqrtf(vr + EPSV);
    #pragma unroll
    for (int k = 0; k < 2; ++k){
      int d = t + k*256;
      e_s[d] = (hv[k] - mu)*rstd*lng[d] + lnb[d];
    }
  }
  __syncthreads();

  // ---- q-proj (this head's 64 dims, K split 4) ----
  {
    int i = t >> 2, part = t & 3;
    const float4* wr = (const float4*)(attw + (size_t)(h*64 + i)*512 + part*128);
    const float* ev = e_s + part*128;
    float a = 0.f;
    #pragma unroll
    for (int j = 0; j < 32; ++j) a += dot4f(wr[j], ev + 4*j);
    a += __shfl_xor(a, 1, 64);
    a += __shfl_xor(a, 2, 64);
    if (part == 0) q_s[i] = a + attb[h*64 + i];
  }
  __syncthreads();

  // ---- scores + softmax ----
  float sc;
  {
    const float4* kr = (const float4*)(kvb + (size_t)t*512 + h*64);
    const float4* qr = (const float4*)q_s;
    float a = 0.f;
    #pragma unroll
    for (int j = 0; j < 16; ++j){
      float4 kk = kr[j], qq = qr[j];
      a += kk.x*qq.x + kk.y*qq.y + kk.z*qq.z + kk.w*qq.w;
    }
    sc = a * 0.125f;
  }
  int wv = t >> 6, lane = t & 63;
  float mx = sc;
  #pragma unroll
  for (int msk = 1; msk < 64; msk <<= 1) mx = fmaxf(mx, __shfl_xor(mx, msk, 64));
  __syncthreads();                 // r2 reuse
  if (lane == 0) r2[wv] = mx;
  __syncthreads();
  mx = fmaxf(fmaxf(r2[0], r2[1]), fmaxf(r2[2], r2[3]));
  float ex = expf(sc - mx);
  float sum = ex;
  #pragma unroll
  for (int msk = 1; msk < 64; msk <<= 1) sum += __shfl_xor(sum, msk, 64);
  if (lane == 0) r2[4 + wv] = sum;
  __syncthreads();
  float inv = 1.f / (r2[4] + r2[5] + r2[6] + r2[7]);
  att_s[t] = ex * inv;
  __syncthreads();

  // ---- ctx ----
  {
    const float* vbase = kvb + 131072 + (size_t)(wv*64)*512 + h*64 + lane;
    const float* at = att_s + wv*64;
    float a = 0.f;
    #pragma unroll 8
    for (int m = 0; m < 64; ++m) a += at[m] * vbase[(size_t)m*512];
    red_s[wv*64 + lane] = a;
  }
  __syncthreads();
  if (t < 64)
    ctxout[(size_t)b*512 + h*64 + t] = red_s[t] + red_s[64+t] + red_s[128+t] + red_s[192+t];
}

// ---------------------------------------------------------------------------
// K4b: out-proj + gate + rec1 + rec2 in ONE kernel. 32 blocks x 512 threads.
// All operands LDS-resident; enc recomputed (identical arithmetic). Replaces
// 4 launches.
__global__ __launch_bounds__(512) void k_tail(
    const float* __restrict__ pp,
    const float* __restrict__ lw, const float* __restrict__ lb,
    const float* __restrict__ lng, const float* __restrict__ lnb,
    const float* __restrict__ ctx,
    const float* __restrict__ ow, const float* __restrict__ obv,
    const float* __restrict__ gw, const float* __restrict__ gb,
    const float* __restrict__ r1w, const float* __restrict__ r1b,
    const float* __restrict__ r2w, const float* __restrict__ r2b,
    float* __restrict__ swout){
  int b = blockIdx.x, t = threadIdx.x;
  int wv = t >> 6;
  __shared__ __align__(16) float p_s[256];
  __shared__ __align__(16) float c_s[512];
  __shared__ __align__(16) float e_s[512];
  __shared__ __align__(16) float r_s[512];
  __shared__ __align__(16) float f_s[512];
  __shared__ __align__(16) float t_s[256];
  __shared__ float red[16];

  c_s[t] = ctx[(size_t)b*512 + t];
  if (t < 256){
    float s = 0.f;
    for (int tile = 0; tile < 64; ++tile) s += pp[(size_t)((b<<6)+tile)*256 + t];
    p_s[t] = s * (1.f/4096.f);
  }
  __syncthreads();

  // ---- enc (512 threads, 1 output each; same op order as k_enc per output) ----
  float hv;
  {
    const float4* wr = (const float4*)(lw + (size_t)t*256);
    float a = 0.f;
    for (int j = 0; j < 64; ++j) a += dot4f(wr[j], &p_s[4*j]);
    hv = a + lb[t];
  }
  {
    float ls = hv, lq = hv*hv;
    #pragma unroll
    for (int msk = 1; msk < 64; msk <<= 1){
      ls += __shfl_xor(ls, msk, 64);
      lq += __shfl_xor(lq, msk, 64);
    }
    if ((t & 63) == 0){ red[wv] = ls; red[8 + wv] = lq; }
    __syncthreads();
    float su = 0.f, sq = 0.f;
    #pragma unroll
    for (int w = 0; w < 8; ++w){ su += red[w]; sq += red[8 + w]; }
    float mu = su * (1.f/512.f);
    float vr = sq * (1.f/512.f) - mu*mu;
    float rstd = rsqrtf(vr + EPSV);
    e_s[t] = (hv - mu)*rstd*lng[t] + lnb[t];
  }
  __syncthreads();

  // ---- retrieved = ctx @ owT + b ----
  {
    const float4* wr = (const float4*)(ow + (size_t)t*512);
    float a = 0.f;
    for (int j = 0; j < 128; ++j) a += dot4f(wr[j], &c_s[4*j]);
    r_s[t] = a + obv[t];
  }
  __syncthreads();

  // ---- gate + fuse ----
  {
    const float4* wr = (const float4*)(gw + (size_t)t*1024);
    float a = 0.f;
    for (int j = 0; j < 128; ++j) a += dot4f(wr[j], &e_s[4*j]);
    for (int j = 0; j < 128; ++j) a += dot4f(wr[128 + j], &r_s[4*j]);
    float g = sigmoidf(a + gb[t]);
    f_s[t] = g*e_s[t] + (1.f - g)*r_s[t];
  }
  __syncthreads();

  // ---- rec1 (relu) ----
  if (t < 256){
    const float4* wr = (const float4*)(r1w + (size_t)t*512);
    float a = 0.f;
    for (int j = 0; j < 128; ++j) a += dot4f(wr[j], &f_s[4*j]);
    t_s[t] = fmaxf(a + r1b[t], 0.f);
  }
  __syncthreads();

  // ---- rec2 (sigmoid) -> sw ----
  if (t < 256){
    const float4* wr = (const float4*)(r2w + (size_t)t*256);
    float a = 0.f;
    for (int j = 0; j < 64; ++j) a += dot4f(wr[j], &t_s[4*j]);
    swout[(size_t)b*256 + t] = sigmoidf(a + r2b[t]);
  }
}

// ---------------------------------------------------------------------------
// K5: 7x7 spatial conv on [avg,max] stats, sigmoid -> sa
__global__ __launch_bounds__(256) void k_spconv(const float* __restrict__ wavg,
    const float* __restrict__ wmax, const float* __restrict__ wgt,
    float* __restrict__ sa){
  __shared__ float w_s[98];
  int t = threadIdx.x;
  if (t < 98) w_s[t] = wgt[t];
  __syncthreads();
  int b = blockIdx.x >> 4;
  int px = ((blockIdx.x & 15) << 8) + t;
  int y = px >> 6, xx = px & 63;
  const float* pa = wavg + (b << 12);
  const float* pm = wmax + (b << 12);
  float a = 0.f;
  #pragma unroll
  for (int ky = 0; ky < 7; ++ky){
    int yy = y + ky - 3;
    if (yy < 0 || yy >= 64) continue;
    #pragma unroll
    for (int kx = 0; kx < 7; ++kx){
      int x2 = xx + kx - 3;
      if (x2 < 0 || x2 >= 64) continue;
      int o = (yy << 6) + x2;
      a += pa[o]*w_s[ky*7+kx] + pm[o]*w_s[49+ky*7+kx];
    }
  }
  sa[(b << 12) + px] = sigmoidf(a);
}

// ---------------------------------------------------------------------------
// K6: out = x * sw[b,c] * sa[b,hw]  — NT x stream / out store
__global__ __launch_bounds__(256) void k_final(const float* __restrict__ x,
    const float* __restrict__ sw, const float* __restrict__ sa,
    float* __restrict__ out){
  const size_t total = 8388608;
  for (size_t q = (size_t)blockIdx.x*256 + threadIdx.x; q < total; q += (size_t)gridDim.x*256){
    size_t b = q >> 18;
    int c = (int)((q >> 10) & 255);
    int p4 = (int)(q & 1023);
    f32x4 xv = __builtin_nontemporal_load((const f32x4*)x + q);
    f32x4 sv = ((const f32x4*)sa)[(b << 10) + p4];
    float s = sw[(b << 8) + c];
    f32x4 o = xv * s * sv;
    __builtin_nontemporal_store(o, (f32x4*)out + q);
  }
}

// ---------------------------------------------------------------------------
extern "C" void kernel_launch(void* const* d_in, const int* in_sizes, int n_in,
                              void* d_out, int out_size, void* d_ws, size_t ws_size,
                              hipStream_t stream){
  const float* x    = (const float*)d_in[0];
  const float* mb   = (const float*)d_in[1];
  const float* w1   = (const float*)d_in[2];
  const float* cbv  = (const float*)d_in[3];
  const float* bng  = (const float*)d_in[4];
  const float* bnb  = (const float*)d_in[5];
  const float* bnm  = (const float*)d_in[6];
  const float* bnv  = (const float*)d_in[7];
  const float* lw   = (const float*)d_in[8];
  const float* lb   = (const float*)d_in[9];
  const float* lng  = (const float*)d_in[10];
  const float* lnb  = (const float*)d_in[11];
  const float* attw = (const float*)d_in[12];
  const float* attb = (const float*)d_in[13];
  const float* ow   = (const float*)d_in[14];
  const float* obv  = (const float*)d_in[15];
  const float* gw   = (const float*)d_in[16];
  const float* gb   = (const float*)d_in[17];
  const float* r1w  = (const float*)d_in[18];
  const float* r1b  = (const float*)d_in[19];
  const float* r2w  = (const float*)d_in[20];
  const float* r2b  = (const float*)d_in[21];
  const float* spw  = (const float*)d_in[22];
  float* out = (float*)d_out;

  char* ws = (char*)d_ws;
  unsigned short* w1p  = (unsigned short*)(ws + 0);        // 128 KiB
  unsigned short* wkvp = (unsigned short*)(ws + 131072);   // 1 MiB
  float* ppool = (float*)(ws + 1179648);                   // 2 MiB
  float* wavg  = (float*)(ws + 3276800);                   // 512 KiB
  float* wmax  = (float*)(ws + 3801088);                   // 512 KiB
  float* kvb   = (float*)(ws + 4390912);                   // 1 MiB
  float* swb   = (float*)(ws + 5439488);                   // 32 KiB
  float* sab   = (float*)(ws + 5472256);                   // 512 KiB
  float* ctxb  = (float*)(ws + 5996544);                   // 64 KiB

  k_pack   <<<2304, 256, 0, stream>>>(w1, attw, w1p, wkvp);
  k_conv   <<<2048, 256, 0, stream>>>(x, w1p, cbv, bng, bnb, bnm, bnv, ppool, wavg, wmax);
  k_kv     <<<256,  256, 0, stream>>>(mb, wkvp, attb, kvb);
  k_qkattn <<<256,  256, 0, stream>>>(ppool, lw, lb, lng, lnb, kvb, attw, attb, ctxb);
  k_tail   <<<32,   512, 0, stream>>>(ppool, lw, lb, lng, lnb, ctxb, ow, obv,
                                      gw, gb, r1w, r1b, r2w, r2b, swb);
  k_spconv <<<512,  256, 0, stream>>>(wavg, wmax, spw, sab);
  k_final  <<<2048, 256, 0, stream>>>(x, swb, sab, out);
}

// Round 13
// 174.533 us; speedup vs baseline: 1.5567x; 1.5567x over previous
//
#include <hip/hip_runtime.h>
#include <math.h>

#define EPSV 1e-5f

typedef __attribute__((ext_vector_type(8))) short short8;
typedef __attribute__((ext_vector_type(8))) unsigned short ushort8;
typedef __attribute__((ext_vector_type(4))) float f32x4;

__device__ __forceinline__ unsigned short f2bf(float f){
  unsigned u = __builtin_bit_cast(unsigned, f);
  u += 0x7fffu + ((u >> 16) & 1u);            // RNE to bf16
  return (unsigned short)(u >> 16);
}
__device__ __forceinline__ float dot4f(float4 w, const float* v){
  return w.x*v[0] + w.y*v[1] + w.z*v[2] + w.w*v[3];
}
__device__ __forceinline__ float sigmoidf(float v){ return 1.f/(1.f + expf(-v)); }

// ---------------------------------------------------------------------------
// Pack weights into MFMA B-fragment-linear bf16.
__global__ __launch_bounds__(256) void k_pack(const float* __restrict__ w1,
                                              const float* __restrict__ wattn,
                                              unsigned short* __restrict__ p1,
                                              unsigned short* __restrict__ pkv){
  const int total1 = 256*256, total2 = 1024*512;
  for (int idx = blockIdx.x*256 + threadIdx.x; idx < total1 + total2; idx += gridDim.x*256){
    if (idx < total1){
      int o = idx >> 8, c = idx & 255;
      int off = (((o>>4)*8 + (c>>5))*64 + (((c>>3)&3)*16 + (o&15)))*8 + (c&7);
      p1[off] = f2bf(w1[idx]);
    } else {
      int j = idx - total1; int o = j >> 9, c = j & 511;
      int off = (((o>>4)*16 + (c>>5))*64 + (((c>>3)&3)*16 + (o&15)))*8 + (c&7);
      pkv[off] = f2bf(wattn[512*512 + j]);
    }
  }
}

// ---------------------------------------------------------------------------
// K1: 1x1 conv (bf16 MFMA) + BN + ReLU + partial avg-pool + channel stats.
// R3 structure + NT x loads. Measured floor ~73 us.
__global__ __launch_bounds__(256) void k_conv(
    const float* __restrict__ x, const unsigned short* __restrict__ wp,
    const float* __restrict__ cb, const float* __restrict__ bng,
    const float* __restrict__ bnb, const float* __restrict__ bnm,
    const float* __restrict__ bnv,
    float* __restrict__ ppool, float* __restrict__ wavg, float* __restrict__ wmax){
  int bid = blockIdx.x;
  int b = bid >> 6, tile = bid & 63;
  int px0 = tile << 6;
  int t = threadIdx.x;
  int lane = t & 63, wv = t >> 6;
  int px = t & 63, cg = wv;
  __shared__ __align__(16) unsigned short a_lds[16384];
  __shared__ float st_s[256], st_m[256];

  const float* xb = x + (size_t)b*(256*4096) + px0 + px;

  float ssum = 0.f, smax = -3.4e38f;
  const unsigned wbase = (((px >> 4) << 6) + ((unsigned)cg << 4) + (px & 15)) << 4;

  #pragma unroll
  for (int ch = 0; ch < 8; ++ch){
    float xv[8];
    #pragma unroll
    for (int u = 0; u < 8; ++u)
      xv[u] = __builtin_nontemporal_load(xb + (size_t)(ch*32 + cg*8 + u) * 4096);
    ushort8 pk;
    #pragma unroll
    for (int u = 0; u < 8; ++u){
      ssum += xv[u];
      smax = fmaxf(smax, xv[u]);
      pk[u] = f2bf(xv[u]);
    }
    *(ushort8*)((char*)a_lds + wbase + (ch << 12)) = pk;
  }
  st_s[t] = ssum; st_m[t] = smax;
  __syncthreads();

  if (t < 64){
    float s = st_s[t] + st_s[t+64] + st_s[t+128] + st_s[t+192];
    float m = fmaxf(fmaxf(st_m[t], st_m[t+64]), fmaxf(st_m[t+128], st_m[t+192]));
    wavg[(b << 12) + px0 + t] = s * (1.f/256.f);
    wmax[(b << 12) + px0 + t] = m;
  }

  f32x4 acc[4][4];
  #pragma unroll
  for (int i = 0; i < 4; ++i)
    #pragma unroll
    for (int j = 0; j < 4; ++j){ f32x4 z = {0.f,0.f,0.f,0.f}; acc[i][j] = z; }

  #pragma unroll
  for (int ch = 0; ch < 8; ++ch){
    short8 afr[4];
    #pragma unroll
    for (int mf = 0; mf < 4; ++mf)
      afr[mf] = *(const short8*)((const char*)a_lds + (ch << 12) + (mf << 10) + lane*16);
    #pragma unroll
    for (int nf = 0; nf < 4; ++nf){
      short8 bfr = *(const short8*)(wp + (size_t)(((wv*4 + nf)*8 + ch) * 512 + lane*8));
      #pragma unroll
      for (int mf = 0; mf < 4; ++mf)
        acc[mf][nf] = __builtin_amdgcn_mfma_f32_16x16x32_bf16(afr[mf], bfr, acc[mf][nf], 0, 0, 0);
    }
  }

  #pragma unroll
  for (int nf = 0; nf < 4; ++nf){
    int o = (wv << 6) + (nf << 4) + (lane & 15);
    float sc = bng[o] * rsqrtf(bnv[o] + EPSV);
    float sh = bnb[o] + (cb[o] - bnm[o]) * sc;
    float ps = 0.f;
    #pragma unroll
    for (int mf = 0; mf < 4; ++mf)
      #pragma unroll
      for (int r = 0; r < 4; ++r)
        ps += fmaxf(acc[mf][nf][r] * sc + sh, 0.f);
    ps += __shfl_xor(ps, 16, 64);
    ps += __shfl_xor(ps, 32, 64);
    if ((lane & 48) == 0)
      ppool[(size_t)((b << 6) + tile)*256 + o] = ps;
  }
}

// ---------------------------------------------------------------------------
// K3: K/V projection of memory bank. Barrier-free, fragments direct from mb.
__global__ __launch_bounds__(256) void k_kv(const float* __restrict__ mb,
    const unsigned short* __restrict__ wp, const float* __restrict__ attb,
    float* __restrict__ kvb){
  int bid = blockIdx.x;
  int mt = bid >> 4, nt = bid & 15;
  int m0 = mt << 4;
  int mu = nt >> 3;
  int ncol0 = (nt & 7) << 6;
  int t = threadIdx.x, lane = t & 63, wv = t >> 6;
  int l15 = lane & 15, l4 = lane >> 4;

  const float* arow = mb + (size_t)(m0 + l15)*512 + l4*8;
  int ofrag = (nt << 2) + wv;

  f32x4 acc = {0.f,0.f,0.f,0.f};
  #pragma unroll
  for (int ch = 0; ch < 16; ++ch){
    float4 a0 = *(const float4*)(arow + ch*32);
    float4 a1 = *(const float4*)(arow + ch*32 + 4);
    short8 afr;
    afr[0] = (short)f2bf(a0.x); afr[1] = (short)f2bf(a0.y);
    afr[2] = (short)f2bf(a0.z); afr[3] = (short)f2bf(a0.w);
    afr[4] = (short)f2bf(a1.x); afr[5] = (short)f2bf(a1.y);
    afr[6] = (short)f2bf(a1.z); afr[7] = (short)f2bf(a1.w);
    short8 bfr = *(const short8*)(wp + (size_t)(ofrag*16 + ch)*512 + lane*8);
    acc = __builtin_amdgcn_mfma_f32_16x16x32_bf16(afr, bfr, acc, 0, 0, 0);
  }
  float bias = attb[512 + mu*512 + ncol0 + (wv << 4) + l15];
  #pragma unroll
  for (int i = 0; i < 4; ++i){
    int row = m0 + l4*4 + i;
    int col = ncol0 + (wv << 4) + l15;
    kvb[(size_t)mu*131072 + (size_t)row*512 + col] = acc[i] + bias;
  }
}

// ---------------------------------------------------------------------------
// K4a: per (b,head): enc (recomputed, h==0 also stores it), q-proj, scores,
// softmax, ctx. grid = 32*8 = 256 blocks.
__global__ __launch_bounds__(256) void k_qkattn(const float* __restrict__ pp,
    const float* __restrict__ lw, const float* __restrict__ lb,
    const float* __restrict__ lng, const float* __restrict__ lnb,
    const float* __restrict__ kvb, const float* __restrict__ attw,
    const float* __restrict__ attb, float* __restrict__ ctxout,
    float* __restrict__ encout){
  int bid = blockIdx.x;
  int b = bid >> 3, h = bid & 7;
  int t = threadIdx.x;
  __shared__ __align__(16) float p_s[256];
  __shared__ float e_s[512];
  __shared__ __align__(16) float q_s[64];
  __shared__ float att_s[256];
  __shared__ float red_s[256];
  __shared__ float r2[8];

  // ---- enc: pool + linear + LayerNorm ----
  {
    float s = 0.f;
    for (int tile = 0; tile < 64; ++tile) s += pp[(size_t)((b<<6)+tile)*256 + t];
    p_s[t] = s * (1.f/4096.f);
  }
  __syncthreads();
  {
    float hv[2];
    #pragma unroll
    for (int k = 0; k < 2; ++k){
      int d = t + k*256;
      const float4* wr = (const float4*)(lw + (size_t)d*256);
      float a = 0.f;
      for (int j = 0; j < 64; ++j) a += dot4f(wr[j], &p_s[4*j]);
      hv[k] = a + lb[d];
    }
    float ls = hv[0] + hv[1], lq = hv[0]*hv[0] + hv[1]*hv[1];
    #pragma unroll
    for (int msk = 1; msk < 64; msk <<= 1){
      ls += __shfl_xor(ls, msk, 64);
      lq += __shfl_xor(lq, msk, 64);
    }
    if ((t & 63) == 0){ r2[t>>6] = ls; r2[4 + (t>>6)] = lq; }
    __syncthreads();
    float su = r2[0]+r2[1]+r2[2]+r2[3];
    float sq = r2[4]+r2[5]+r2[6]+r2[7];
    float mu = su * (1.f/512.f);
    float vr = sq * (1.f/512.f) - mu*mu;
    float rstd = rsqrtf(vr + EPSV);
    #pragma unroll
    for (int k = 0; k < 2; ++k){
      int d = t + k*256;
      e_s[d] = (hv[k] - mu)*rstd*lng[d] + lnb[d];
    }
  }
  __syncthreads();
  if (h == 0){
    encout[(size_t)b*512 + t]       = e_s[t];
    encout[(size_t)b*512 + 256 + t] = e_s[t + 256];
  }

  // ---- q-proj (this head's 64 dims, K split 4) ----
  {
    int i = t >> 2, part = t & 3;
    const float4* wr = (const float4*)(attw + (size_t)(h*64 + i)*512 + part*128);
    const float* ev = e_s + part*128;
    float a = 0.f;
    #pragma unroll
    for (int j = 0; j < 32; ++j) a += dot4f(wr[j], ev + 4*j);
    a += __shfl_xor(a, 1, 64);
    a += __shfl_xor(a, 2, 64);
    if (part == 0) q_s[i] = a + attb[h*64 + i];
  }
  __syncthreads();

  // ---- scores + softmax ----
  float sc;
  {
    const float4* kr = (const float4*)(kvb + (size_t)t*512 + h*64);
    const float4* qr = (const float4*)q_s;
    float a = 0.f;
    #pragma unroll
    for (int j = 0; j < 16; ++j){
      float4 kk = kr[j], qq = qr[j];
      a += kk.x*qq.x + kk.y*qq.y + kk.z*qq.z + kk.w*qq.w;
    }
    sc = a * 0.125f;
  }
  int wv = t >> 6, lane = t & 63;
  float mx = sc;
  #pragma unroll
  for (int msk = 1; msk < 64; msk <<= 1) mx = fmaxf(mx, __shfl_xor(mx, msk, 64));
  __syncthreads();
  if (lane == 0) r2[wv] = mx;
  __syncthreads();
  mx = fmaxf(fmaxf(r2[0], r2[1]), fmaxf(r2[2], r2[3]));
  float ex = expf(sc - mx);
  float sum = ex;
  #pragma unroll
  for (int msk = 1; msk < 64; msk <<= 1) sum += __shfl_xor(sum, msk, 64);
  if (lane == 0) r2[4 + wv] = sum;
  __syncthreads();
  float inv = 1.f / (r2[4] + r2[5] + r2[6] + r2[7]);
  att_s[t] = ex * inv;
  __syncthreads();

  // ---- ctx ----
  {
    const float* vbase = kvb + 131072 + (size_t)(wv*64)*512 + h*64 + lane;
    const float* at = att_s + wv*64;
    float a = 0.f;
    #pragma unroll 8
    for (int m = 0; m < 64; ++m) a += at[m] * vbase[(size_t)m*512];
    red_s[wv*64 + lane] = a;
  }
  __syncthreads();
  if (t < 64)
    ctxout[(size_t)b*512 + h*64 + t] = red_s[t] + red_s[64+t] + red_s[128+t] + red_s[192+t];
}

// ---------------------------------------------------------------------------
// K4b: retrieved = ctx @ owT + b. grid = 32*8; block computes 64 outputs.
__global__ __launch_bounds__(256) void k_outproj(const float* __restrict__ ctx,
    const float* __restrict__ ow, const float* __restrict__ obv,
    float* __restrict__ retr){
  int bid = blockIdx.x;
  int b = bid >> 3, n0 = (bid & 7) << 6;
  int t = threadIdx.x;
  __shared__ float c_s[512];
  c_s[t]       = ctx[(size_t)b*512 + t];
  c_s[t + 256] = ctx[(size_t)b*512 + 256 + t];
  __syncthreads();
  int o = n0 + (t >> 2), part = t & 3;
  const float4* wr = (const float4*)(ow + (size_t)o*512 + part*128);
  const float* cv = c_s + part*128;
  float a = 0.f;
  #pragma unroll
  for (int j = 0; j < 32; ++j) a += dot4f(wr[j], cv + 4*j);
  a += __shfl_xor(a, 1, 64);
  a += __shfl_xor(a, 2, 64);
  if (part == 0) retr[(size_t)b*512 + o] = a + obv[o];
}

// ---------------------------------------------------------------------------
// K4c: gate + fuse. grid = 32*8; 64 outputs per block, K=1024 split 4.
__global__ __launch_bounds__(256) void k_gate(const float* __restrict__ enc,
    const float* __restrict__ retr, const float* __restrict__ gw,
    const float* __restrict__ gb, float* __restrict__ fused){
  int bid = blockIdx.x;
  int b = bid >> 3, n0 = (bid & 7) << 6;
  int t = threadIdx.x;
  __shared__ float ef[1024];
  ef[t]        = enc[(size_t)b*512 + t];
  ef[t + 256]  = enc[(size_t)b*512 + 256 + t];
  ef[t + 512]  = retr[(size_t)b*512 + t];
  ef[t + 768]  = retr[(size_t)b*512 + 256 + t];
  __syncthreads();
  int o = n0 + (t >> 2), part = t & 3;
  const float4* wr = (const float4*)(gw + (size_t)o*1024 + part*256);
  const float* fv = ef + part*256;
  float a = 0.f;
  #pragma unroll
  for (int j = 0; j < 64; ++j) a += dot4f(wr[j], fv + 4*j);
  a += __shfl_xor(a, 1, 64);
  a += __shfl_xor(a, 2, 64);
  if (part == 0){
    float g = sigmoidf(a + gb[o]);
    fused[(size_t)b*512 + o] = g*ef[o] + (1.f - g)*ef[512 + o];
  }
}

// ---------------------------------------------------------------------------
// K4d: rec1 = relu(fused @ r1wT + b). grid = 32*4; 64 outputs, K=512 split 4.
__global__ __launch_bounds__(256) void k_rec1(const float* __restrict__ fused,
    const float* __restrict__ r1w, const float* __restrict__ r1b,
    float* __restrict__ t1){
  int bid = blockIdx.x;
  int b = bid >> 2, n0 = (bid & 3) << 6;
  int t = threadIdx.x;
  __shared__ float f_s[512];
  f_s[t]       = fused[(size_t)b*512 + t];
  f_s[t + 256] = fused[(size_t)b*512 + 256 + t];
  __syncthreads();
  int o = n0 + (t >> 2), part = t & 3;
  const float4* wr = (const float4*)(r1w + (size_t)o*512 + part*128);
  const float* fv = f_s + part*128;
  float a = 0.f;
  #pragma unroll
  for (int j = 0; j < 32; ++j) a += dot4f(wr[j], fv + 4*j);
  a += __shfl_xor(a, 1, 64);
  a += __shfl_xor(a, 2, 64);
  if (part == 0) t1[(size_t)b*256 + o] = fmaxf(a + r1b[o], 0.f);
}

// ---------------------------------------------------------------------------
// K4e: sw = sigmoid(t1 @ r2wT + b). grid = 32*4; 64 outputs, K=256 split 4.
__global__ __launch_bounds__(256) void k_rec2(const float* __restrict__ t1,
    const float* __restrict__ r2w, const float* __restrict__ r2b,
    float* __restrict__ swout){
  int bid = blockIdx.x;
  int b = bid >> 2, n0 = (bid & 3) << 6;
  int t = threadIdx.x;
  __shared__ float t_s[256];
  t_s[t] = t1[(size_t)b*256 + t];
  __syncthreads();
  int o = n0 + (t >> 2), part = t & 3;
  const float4* wr = (const float4*)(r2w + (size_t)o*256 + part*64);
  const float* tv = t_s + part*64;
  float a = 0.f;
  #pragma unroll
  for (int j = 0; j < 16; ++j) a += dot4f(wr[j], tv + 4*j);
  a += __shfl_xor(a, 1, 64);
  a += __shfl_xor(a, 2, 64);
  if (part == 0) swout[(size_t)b*256 + o] = sigmoidf(a + r2b[o]);
}

// ---------------------------------------------------------------------------
// K5: 7x7 spatial conv on [avg,max] stats, sigmoid -> sa
__global__ __launch_bounds__(256) void k_spconv(const float* __restrict__ wavg,
    const float* __restrict__ wmax, const float* __restrict__ wgt,
    float* __restrict__ sa){
  __shared__ float w_s[98];
  int t = threadIdx.x;
  if (t < 98) w_s[t] = wgt[t];
  __syncthreads();
  int b = blockIdx.x >> 4;
  int px = ((blockIdx.x & 15) << 8) + t;
  int y = px >> 6, xx = px & 63;
  const float* pa = wavg + (b << 12);
  const float* pm = wmax + (b << 12);
  float a = 0.f;
  #pragma unroll
  for (int ky = 0; ky < 7; ++ky){
    int yy = y + ky - 3;
    if (yy < 0 || yy >= 64) continue;
    #pragma unroll
    for (int kx = 0; kx < 7; ++kx){
      int x2 = xx + kx - 3;
      if (x2 < 0 || x2 >= 64) continue;
      int o = (yy << 6) + x2;
      a += pa[o]*w_s[ky*7+kx] + pm[o]*w_s[49+ky*7+kx];
    }
  }
  sa[(b << 12) + px] = sigmoidf(a);
}

// ---------------------------------------------------------------------------
// K6: out = x * sw[b,c] * sa[b,hw]  — NT x stream / out store
__global__ __launch_bounds__(256) void k_final(const float* __restrict__ x,
    const float* __restrict__ sw, const float* __restrict__ sa,
    float* __restrict__ out){
  const size_t total = 8388608;
  for (size_t q = (size_t)blockIdx.x*256 + threadIdx.x; q < total; q += (size_t)gridDim.x*256){
    size_t b = q >> 18;
    int c = (int)((q >> 10) & 255);
    int p4 = (int)(q & 1023);
    f32x4 xv = __builtin_nontemporal_load((const f32x4*)x + q);
    f32x4 sv = ((const f32x4*)sa)[(b << 10) + p4];
    float s = sw[(b << 8) + c];
    f32x4 o = xv * s * sv;
    __builtin_nontemporal_store(o, (f32x4*)out + q);
  }
}

// ---------------------------------------------------------------------------
extern "C" void kernel_launch(void* const* d_in, const int* in_sizes, int n_in,
                              void* d_out, int out_size, void* d_ws, size_t ws_size,
                              hipStream_t stream){
  const float* x    = (const float*)d_in[0];
  const float* mb   = (const float*)d_in[1];
  const float* w1   = (const float*)d_in[2];
  const float* cbv  = (const float*)d_in[3];
  const float* bng  = (const float*)d_in[4];
  const float* bnb  = (const float*)d_in[5];
  const float* bnm  = (const float*)d_in[6];
  const float* bnv  = (const float*)d_in[7];
  const float* lw   = (const float*)d_in[8];
  const float* lb   = (const float*)d_in[9];
  const float* lng  = (const float*)d_in[10];
  const float* lnb  = (const float*)d_in[11];
  const float* attw = (const float*)d_in[12];
  const float* attb = (const float*)d_in[13];
  const float* ow   = (const float*)d_in[14];
  const float* obv  = (const float*)d_in[15];
  const float* gw   = (const float*)d_in[16];
  const float* gb   = (const float*)d_in[17];
  const float* r1w  = (const float*)d_in[18];
  const float* r1b  = (const float*)d_in[19];
  const float* r2w  = (const float*)d_in[20];
  const float* r2b  = (const float*)d_in[21];
  const float* spw  = (const float*)d_in[22];
  float* out = (float*)d_out;

  char* ws = (char*)d_ws;
  unsigned short* w1p  = (unsigned short*)(ws + 0);        // 128 KiB
  unsigned short* wkvp = (unsigned short*)(ws + 131072);   // 1 MiB
  float* ppool = (float*)(ws + 1179648);                   // 2 MiB
  float* wavg  = (float*)(ws + 3276800);                   // 512 KiB
  float* wmax  = (float*)(ws + 3801088);                   // 512 KiB
  float* encb  = (float*)(ws + 4325376);                   // 64 KiB
  float* kvb   = (float*)(ws + 4390912);                   // 1 MiB
  float* swb   = (float*)(ws + 5439488);                   // 32 KiB
  float* sab   = (float*)(ws + 5472256);                   // 512 KiB
  float* ctxb  = (float*)(ws + 5996544);                   // 64 KiB
  float* retrb = (float*)(ws + 6062080);                   // 64 KiB
  float* fusedb= (float*)(ws + 6127616);                   // 64 KiB
  float* t1b   = (float*)(ws + 6193152);                   // 32 KiB

  k_pack   <<<2304, 256, 0, stream>>>(w1, attw, w1p, wkvp);
  k_conv   <<<2048, 256, 0, stream>>>(x, w1p, cbv, bng, bnb, bnm, bnv, ppool, wavg, wmax);
  k_kv     <<<256,  256, 0, stream>>>(mb, wkvp, attb, kvb);
  k_qkattn <<<256,  256, 0, stream>>>(ppool, lw, lb, lng, lnb, kvb, attw, attb, ctxb, encb);
  k_outproj<<<256,  256, 0, stream>>>(ctxb, ow, obv, retrb);
  k_gate   <<<256,  256, 0, stream>>>(encb, retrb, gw, gb, fusedb);
  k_rec1   <<<128,  256, 0, stream>>>(fusedb, r1w, r1b, t1b);
  k_rec2   <<<128,  256, 0, stream>>>(t1b, r2w, r2b, swb);
  k_spconv <<<512,  256, 0, stream>>>(wavg, wmax, spw, sab);
  k_final  <<<2048, 256, 0, stream>>>(x, swb, sab, out);
}

// Round 14
// 167.590 us; speedup vs baseline: 1.6212x; 1.0414x over previous
//
#include <hip/hip_runtime.h>
#include <math.h>

#define EPSV 1e-5f

typedef __attribute__((ext_vector_type(8))) short short8;
typedef __attribute__((ext_vector_type(8))) unsigned short ushort8;
typedef __attribute__((ext_vector_type(4))) float f32x4;

__device__ __forceinline__ unsigned short f2bf(float f){
  unsigned u = __builtin_bit_cast(unsigned, f);
  u += 0x7fffu + ((u >> 16) & 1u);            // RNE to bf16
  return (unsigned short)(u >> 16);
}
__device__ __forceinline__ float dot4f(float4 w, const float* v){
  return w.x*v[0] + w.y*v[1] + w.z*v[2] + w.w*v[3];
}
__device__ __forceinline__ float sigmoidf(float v){ return 1.f/(1.f + expf(-v)); }

// ---------------------------------------------------------------------------
// Pack weights into MFMA B-fragment-linear bf16.
__global__ __launch_bounds__(256) void k_pack(const float* __restrict__ w1,
                                              const float* __restrict__ wattn,
                                              unsigned short* __restrict__ p1,
                                              unsigned short* __restrict__ pkv){
  const int total1 = 256*256, total2 = 1024*512;
  for (int idx = blockIdx.x*256 + threadIdx.x; idx < total1 + total2; idx += gridDim.x*256){
    if (idx < total1){
      int o = idx >> 8, c = idx & 255;
      int off = (((o>>4)*8 + (c>>5))*64 + (((c>>3)&3)*16 + (o&15)))*8 + (c&7);
      p1[off] = f2bf(w1[idx]);
    } else {
      int j = idx - total1; int o = j >> 9, c = j & 511;
      int off = (((o>>4)*16 + (c>>5))*64 + (((c>>3)&3)*16 + (o&15)))*8 + (c&7);
      pkv[off] = f2bf(wattn[512*512 + j]);
    }
  }
}

// ---------------------------------------------------------------------------
// K1: 1x1 conv (bf16 MFMA) + BN + ReLU + partial avg-pool + channel stats.
// R13 structure, but loads hoisted into two 32-deep register batches so each
// wave keeps 32 VMEM ops in flight (4x the prior depth) — targets the
// outstanding-request starvation that capped effective BW at ~1.8 TB/s.
__global__ __launch_bounds__(256, 4) void k_conv(
    const float* __restrict__ x, const unsigned short* __restrict__ wp,
    const float* __restrict__ cb, const float* __restrict__ bng,
    const float* __restrict__ bnb, const float* __restrict__ bnm,
    const float* __restrict__ bnv,
    float* __restrict__ ppool, float* __restrict__ wavg, float* __restrict__ wmax){
  int bid = blockIdx.x;
  int b = bid >> 6, tile = bid & 63;
  int px0 = tile << 6;
  int t = threadIdx.x;
  int lane = t & 63, wv = t >> 6;
  int px = t & 63, cg = wv;
  __shared__ __align__(16) unsigned short a_lds[16384];
  __shared__ float st_s[256], st_m[256];

  const float* xb = x + (size_t)b*(256*4096) + px0 + px;

  float ssum = 0.f, smax = -3.4e38f;
  const unsigned wbase = (((px >> 4) << 6) + ((unsigned)cg << 4) + (px & 15)) << 4;

  #pragma unroll
  for (int half = 0; half < 2; ++half){
    float xv[32];
    #pragma unroll
    for (int u = 0; u < 32; ++u){
      int ch = half*4 + (u >> 3);                    // chunk 0..7
      xv[u] = __builtin_nontemporal_load(xb + (size_t)(ch*32 + cg*8 + (u & 7)) * 4096);
    }
    #pragma unroll
    for (int c = 0; c < 4; ++c){
      ushort8 pk;
      #pragma unroll
      for (int j = 0; j < 8; ++j){
        float v = xv[c*8 + j];
        ssum += v;
        smax = fmaxf(smax, v);
        pk[j] = f2bf(v);
      }
      *(ushort8*)((char*)a_lds + wbase + ((unsigned)(half*4 + c) << 12)) = pk;
    }
  }
  st_s[t] = ssum; st_m[t] = smax;
  __syncthreads();

  if (t < 64){
    float s = st_s[t] + st_s[t+64] + st_s[t+128] + st_s[t+192];
    float m = fmaxf(fmaxf(st_m[t], st_m[t+64]), fmaxf(st_m[t+128], st_m[t+192]));
    wavg[(b << 12) + px0 + t] = s * (1.f/256.f);
    wmax[(b << 12) + px0 + t] = m;
  }

  f32x4 acc[4][4];
  #pragma unroll
  for (int i = 0; i < 4; ++i)
    #pragma unroll
    for (int j = 0; j < 4; ++j){ f32x4 z = {0.f,0.f,0.f,0.f}; acc[i][j] = z; }

  #pragma unroll
  for (int ch = 0; ch < 8; ++ch){
    short8 afr[4];
    #pragma unroll
    for (int mf = 0; mf < 4; ++mf)
      afr[mf] = *(const short8*)((const char*)a_lds + (ch << 12) + (mf << 10) + lane*16);
    #pragma unroll
    for (int nf = 0; nf < 4; ++nf){
      short8 bfr = *(const short8*)(wp + (size_t)(((wv*4 + nf)*8 + ch) * 512 + lane*8));
      #pragma unroll
      for (int mf = 0; mf < 4; ++mf)
        acc[mf][nf] = __builtin_amdgcn_mfma_f32_16x16x32_bf16(afr[mf], bfr, acc[mf][nf], 0, 0, 0);
    }
  }

  #pragma unroll
  for (int nf = 0; nf < 4; ++nf){
    int o = (wv << 6) + (nf << 4) + (lane & 15);
    float sc = bng[o] * rsqrtf(bnv[o] + EPSV);
    float sh = bnb[o] + (cb[o] - bnm[o]) * sc;
    float ps = 0.f;
    #pragma unroll
    for (int mf = 0; mf < 4; ++mf)
      #pragma unroll
      for (int r = 0; r < 4; ++r)
        ps += fmaxf(acc[mf][nf][r] * sc + sh, 0.f);
    ps += __shfl_xor(ps, 16, 64);
    ps += __shfl_xor(ps, 32, 64);
    if ((lane & 48) == 0)
      ppool[(size_t)((b << 6) + tile)*256 + o] = ps;
  }
}

// ---------------------------------------------------------------------------
// K3: K/V projection of memory bank. Barrier-free, fragments direct from mb.
__global__ __launch_bounds__(256) void k_kv(const float* __restrict__ mb,
    const unsigned short* __restrict__ wp, const float* __restrict__ attb,
    float* __restrict__ kvb){
  int bid = blockIdx.x;
  int mt = bid >> 4, nt = bid & 15;
  int m0 = mt << 4;
  int mu = nt >> 3;
  int ncol0 = (nt & 7) << 6;
  int t = threadIdx.x, lane = t & 63, wv = t >> 6;
  int l15 = lane & 15, l4 = lane >> 4;

  const float* arow = mb + (size_t)(m0 + l15)*512 + l4*8;
  int ofrag = (nt << 2) + wv;

  f32x4 acc = {0.f,0.f,0.f,0.f};
  #pragma unroll
  for (int ch = 0; ch < 16; ++ch){
    float4 a0 = *(const float4*)(arow + ch*32);
    float4 a1 = *(const float4*)(arow + ch*32 + 4);
    short8 afr;
    afr[0] = (short)f2bf(a0.x); afr[1] = (short)f2bf(a0.y);
    afr[2] = (short)f2bf(a0.z); afr[3] = (short)f2bf(a0.w);
    afr[4] = (short)f2bf(a1.x); afr[5] = (short)f2bf(a1.y);
    afr[6] = (short)f2bf(a1.z); afr[7] = (short)f2bf(a1.w);
    short8 bfr = *(const short8*)(wp + (size_t)(ofrag*16 + ch)*512 + lane*8);
    acc = __builtin_amdgcn_mfma_f32_16x16x32_bf16(afr, bfr, acc, 0, 0, 0);
  }
  float bias = attb[512 + mu*512 + ncol0 + (wv << 4) + l15];
  #pragma unroll
  for (int i = 0; i < 4; ++i){
    int row = m0 + l4*4 + i;
    int col = ncol0 + (wv << 4) + l15;
    kvb[(size_t)mu*131072 + (size_t)row*512 + col] = acc[i] + bias;
  }
}

// ---------------------------------------------------------------------------
// K4a: per (b,head): enc (recomputed, h==0 also stores it), q-proj, scores,
// softmax, ctx. grid = 32*8 = 256 blocks.
__global__ __launch_bounds__(256) void k_qkattn(const float* __restrict__ pp,
    const float* __restrict__ lw, const float* __restrict__ lb,
    const float* __restrict__ lng, const float* __restrict__ lnb,
    const float* __restrict__ kvb, const float* __restrict__ attw,
    const float* __restrict__ attb, float* __restrict__ ctxout,
    float* __restrict__ encout){
  int bid = blockIdx.x;
  int b = bid >> 3, h = bid & 7;
  int t = threadIdx.x;
  __shared__ __align__(16) float p_s[256];
  __shared__ float e_s[512];
  __shared__ __align__(16) float q_s[64];
  __shared__ float att_s[256];
  __shared__ float red_s[256];
  __shared__ float r2[8];

  // ---- enc: pool + linear + LayerNorm ----
  {
    float s = 0.f;
    for (int tile = 0; tile < 64; ++tile) s += pp[(size_t)((b<<6)+tile)*256 + t];
    p_s[t] = s * (1.f/4096.f);
  }
  __syncthreads();
  {
    float hv[2];
    #pragma unroll
    for (int k = 0; k < 2; ++k){
      int d = t + k*256;
      const float4* wr = (const float4*)(lw + (size_t)d*256);
      float a = 0.f;
      for (int j = 0; j < 64; ++j) a += dot4f(wr[j], &p_s[4*j]);
      hv[k] = a + lb[d];
    }
    float ls = hv[0] + hv[1], lq = hv[0]*hv[0] + hv[1]*hv[1];
    #pragma unroll
    for (int msk = 1; msk < 64; msk <<= 1){
      ls += __shfl_xor(ls, msk, 64);
      lq += __shfl_xor(lq, msk, 64);
    }
    if ((t & 63) == 0){ r2[t>>6] = ls; r2[4 + (t>>6)] = lq; }
    __syncthreads();
    float su = r2[0]+r2[1]+r2[2]+r2[3];
    float sq = r2[4]+r2[5]+r2[6]+r2[7];
    float mu = su * (1.f/512.f);
    float vr = sq * (1.f/512.f) - mu*mu;
    float rstd = rsqrtf(vr + EPSV);
    #pragma unroll
    for (int k = 0; k < 2; ++k){
      int d = t + k*256;
      e_s[d] = (hv[k] - mu)*rstd*lng[d] + lnb[d];
    }
  }
  __syncthreads();
  if (h == 0){
    encout[(size_t)b*512 + t]       = e_s[t];
    encout[(size_t)b*512 + 256 + t] = e_s[t + 256];
  }

  // ---- q-proj (this head's 64 dims, K split 4) ----
  {
    int i = t >> 2, part = t & 3;
    const float4* wr = (const float4*)(attw + (size_t)(h*64 + i)*512 + part*128);
    const float* ev = e_s + part*128;
    float a = 0.f;
    #pragma unroll
    for (int j = 0; j < 32; ++j) a += dot4f(wr[j], ev + 4*j);
    a += __shfl_xor(a, 1, 64);
    a += __shfl_xor(a, 2, 64);
    if (part == 0) q_s[i] = a + attb[h*64 + i];
  }
  __syncthreads();

  // ---- scores + softmax ----
  float sc;
  {
    const float4* kr = (const float4*)(kvb + (size_t)t*512 + h*64);
    const float4* qr = (const float4*)q_s;
    float a = 0.f;
    #pragma unroll
    for (int j = 0; j < 16; ++j){
      float4 kk = kr[j], qq = qr[j];
      a += kk.x*qq.x + kk.y*qq.y + kk.z*qq.z + kk.w*qq.w;
    }
    sc = a * 0.125f;
  }
  int wv = t >> 6, lane = t & 63;
  float mx = sc;
  #pragma unroll
  for (int msk = 1; msk < 64; msk <<= 1) mx = fmaxf(mx, __shfl_xor(mx, msk, 64));
  __syncthreads();
  if (lane == 0) r2[wv] = mx;
  __syncthreads();
  mx = fmaxf(fmaxf(r2[0], r2[1]), fmaxf(r2[2], r2[3]));
  float ex = expf(sc - mx);
  float sum = ex;
  #pragma unroll
  for (int msk = 1; msk < 64; msk <<= 1) sum += __shfl_xor(sum, msk, 64);
  if (lane == 0) r2[4 + wv] = sum;
  __syncthreads();
  float inv = 1.f / (r2[4] + r2[5] + r2[6] + r2[7]);
  att_s[t] = ex * inv;
  __syncthreads();

  // ---- ctx ----
  {
    const float* vbase = kvb + 131072 + (size_t)(wv*64)*512 + h*64 + lane;
    const float* at = att_s + wv*64;
    float a = 0.f;
    #pragma unroll 8
    for (int m = 0; m < 64; ++m) a += at[m] * vbase[(size_t)m*512];
    red_s[wv*64 + lane] = a;
  }
  __syncthreads();
  if (t < 64)
    ctxout[(size_t)b*512 + h*64 + t] = red_s[t] + red_s[64+t] + red_s[128+t] + red_s[192+t];
}

// ---------------------------------------------------------------------------
// K4b: retrieved = ctx @ owT + b. grid = 32*8; block computes 64 outputs.
__global__ __launch_bounds__(256) void k_outproj(const float* __restrict__ ctx,
    const float* __restrict__ ow, const float* __restrict__ obv,
    float* __restrict__ retr){
  int bid = blockIdx.x;
  int b = bid >> 3, n0 = (bid & 7) << 6;
  int t = threadIdx.x;
  __shared__ float c_s[512];
  c_s[t]       = ctx[(size_t)b*512 + t];
  c_s[t + 256] = ctx[(size_t)b*512 + 256 + t];
  __syncthreads();
  int o = n0 + (t >> 2), part = t & 3;
  const float4* wr = (const float4*)(ow + (size_t)o*512 + part*128);
  const float* cv = c_s + part*128;
  float a = 0.f;
  #pragma unroll
  for (int j = 0; j < 32; ++j) a += dot4f(wr[j], cv + 4*j);
  a += __shfl_xor(a, 1, 64);
  a += __shfl_xor(a, 2, 64);
  if (part == 0) retr[(size_t)b*512 + o] = a + obv[o];
}

// ---------------------------------------------------------------------------
// K4c: gate + fuse. grid = 32*8; 64 outputs per block, K=1024 split 4.
__global__ __launch_bounds__(256) void k_gate(const float* __restrict__ enc,
    const float* __restrict__ retr, const float* __restrict__ gw,
    const float* __restrict__ gb, float* __restrict__ fused){
  int bid = blockIdx.x;
  int b = bid >> 3, n0 = (bid & 7) << 6;
  int t = threadIdx.x;
  __shared__ float ef[1024];
  ef[t]        = enc[(size_t)b*512 + t];
  ef[t + 256]  = enc[(size_t)b*512 + 256 + t];
  ef[t + 512]  = retr[(size_t)b*512 + t];
  ef[t + 768]  = retr[(size_t)b*512 + 256 + t];
  __syncthreads();
  int o = n0 + (t >> 2), part = t & 3;
  const float4* wr = (const float4*)(gw + (size_t)o*1024 + part*256);
  const float* fv = ef + part*256;
  float a = 0.f;
  #pragma unroll
  for (int j = 0; j < 64; ++j) a += dot4f(wr[j], fv + 4*j);
  a += __shfl_xor(a, 1, 64);
  a += __shfl_xor(a, 2, 64);
  if (part == 0){
    float g = sigmoidf(a + gb[o]);
    fused[(size_t)b*512 + o] = g*ef[o] + (1.f - g)*ef[512 + o];
  }
}

// ---------------------------------------------------------------------------
// K4d: rec1 = relu(fused @ r1wT + b). grid = 32*4; 64 outputs, K=512 split 4.
__global__ __launch_bounds__(256) void k_rec1(const float* __restrict__ fused,
    const float* __restrict__ r1w, const float* __restrict__ r1b,
    float* __restrict__ t1){
  int bid = blockIdx.x;
  int b = bid >> 2, n0 = (bid & 3) << 6;
  int t = threadIdx.x;
  __shared__ float f_s[512];
  f_s[t]       = fused[(size_t)b*512 + t];
  f_s[t + 256] = fused[(size_t)b*512 + 256 + t];
  __syncthreads();
  int o = n0 + (t >> 2), part = t & 3;
  const float4* wr = (const float4*)(r1w + (size_t)o*512 + part*128);
  const float* fv = f_s + part*128;
  float a = 0.f;
  #pragma unroll
  for (int j = 0; j < 32; ++j) a += dot4f(wr[j], fv + 4*j);
  a += __shfl_xor(a, 1, 64);
  a += __shfl_xor(a, 2, 64);
  if (part == 0) t1[(size_t)b*256 + o] = fmaxf(a + r1b[o], 0.f);
}

// ---------------------------------------------------------------------------
// K4e: sw = sigmoid(t1 @ r2wT + b). grid = 32*4; 64 outputs, K=256 split 4.
__global__ __launch_bounds__(256) void k_rec2(const float* __restrict__ t1,
    const float* __restrict__ r2w, const float* __restrict__ r2b,
    float* __restrict__ swout){
  int bid = blockIdx.x;
  int b = bid >> 2, n0 = (bid & 3) << 6;
  int t = threadIdx.x;
  __shared__ float t_s[256];
  t_s[t] = t1[(size_t)b*256 + t];
  __syncthreads();
  int o = n0 + (t >> 2), part = t & 3;
  const float4* wr = (const float4*)(r2w + (size_t)o*256 + part*64);
  const float* tv = t_s + part*64;
  float a = 0.f;
  #pragma unroll
  for (int j = 0; j < 16; ++j) a += dot4f(wr[j], tv + 4*j);
  a += __shfl_xor(a, 1, 64);
  a += __shfl_xor(a, 2, 64);
  if (part == 0) swout[(size_t)b*256 + o] = sigmoidf(a + r2b[o]);
}

// ---------------------------------------------------------------------------
// K5: 7x7 spatial conv on [avg,max] stats, sigmoid -> sa
__global__ __launch_bounds__(256) void k_spconv(const float* __restrict__ wavg,
    const float* __restrict__ wmax, const float* __restrict__ wgt,
    float* __restrict__ sa){
  __shared__ float w_s[98];
  int t = threadIdx.x;
  if (t < 98) w_s[t] = wgt[t];
  __syncthreads();
  int b = blockIdx.x >> 4;
  int px = ((blockIdx.x & 15) << 8) + t;
  int y = px >> 6, xx = px & 63;
  const float* pa = wavg + (b << 12);
  const float* pm = wmax + (b << 12);
  float a = 0.f;
  #pragma unroll
  for (int ky = 0; ky < 7; ++ky){
    int yy = y + ky - 3;
    if (yy < 0 || yy >= 64) continue;
    #pragma unroll
    for (int kx = 0; kx < 7; ++kx){
      int x2 = xx + kx - 3;
      if (x2 < 0 || x2 >= 64) continue;
      int o = (yy << 6) + x2;
      a += pa[o]*w_s[ky*7+kx] + pm[o]*w_s[49+ky*7+kx];
    }
  }
  sa[(b << 12) + px] = sigmoidf(a);
}

// ---------------------------------------------------------------------------
// K6: out = x * sw[b,c] * sa[b,hw]  — NT x stream / out store
__global__ __launch_bounds__(256) void k_final(const float* __restrict__ x,
    const float* __restrict__ sw, const float* __restrict__ sa,
    float* __restrict__ out){
  const size_t total = 8388608;
  for (size_t q = (size_t)blockIdx.x*256 + threadIdx.x; q < total; q += (size_t)gridDim.x*256){
    size_t b = q >> 18;
    int c = (int)((q >> 10) & 255);
    int p4 = (int)(q & 1023);
    f32x4 xv = __builtin_nontemporal_load((const f32x4*)x + q);
    f32x4 sv = ((const f32x4*)sa)[(b << 10) + p4];
    float s = sw[(b << 8) + c];
    f32x4 o = xv * s * sv;
    __builtin_nontemporal_store(o, (f32x4*)out + q);
  }
}

// ---------------------------------------------------------------------------
extern "C" void kernel_launch(void* const* d_in, const int* in_sizes, int n_in,
                              void* d_out, int out_size, void* d_ws, size_t ws_size,
                              hipStream_t stream){
  const float* x    = (const float*)d_in[0];
  const float* mb   = (const float*)d_in[1];
  const float* w1   = (const float*)d_in[2];
  const float* cbv  = (const float*)d_in[3];
  const float* bng  = (const float*)d_in[4];
  const float* bnb  = (const float*)d_in[5];
  const float* bnm  = (const float*)d_in[6];
  const float* bnv  = (const float*)d_in[7];
  const float* lw   = (const float*)d_in[8];
  const float* lb   = (const float*)d_in[9];
  const float* lng  = (const float*)d_in[10];
  const float* lnb  = (const float*)d_in[11];
  const float* attw = (const float*)d_in[12];
  const float* attb = (const float*)d_in[13];
  const float* ow   = (const float*)d_in[14];
  const float* obv  = (const float*)d_in[15];
  const float* gw   = (const float*)d_in[16];
  const float* gb   = (const float*)d_in[17];
  const float* r1w  = (const float*)d_in[18];
  const float* r1b  = (const float*)d_in[19];
  const float* r2w  = (const float*)d_in[20];
  const float* r2b  = (const float*)d_in[21];
  const float* spw  = (const float*)d_in[22];
  float* out = (float*)d_out;

  char* ws = (char*)d_ws;
  unsigned short* w1p  = (unsigned short*)(ws + 0);        // 128 KiB
  unsigned short* wkvp = (unsigned short*)(ws + 131072);   // 1 MiB
  float* ppool = (float*)(ws + 1179648);                   // 2 MiB
  float* wavg  = (float*)(ws + 3276800);                   // 512 KiB
  float* wmax  = (float*)(ws + 3801088);                   // 512 KiB
  float* encb  = (float*)(ws + 4325376);                   // 64 KiB
  float* kvb   = (float*)(ws + 4390912);                   // 1 MiB
  float* swb   = (float*)(ws + 5439488);                   // 32 KiB
  float* sab   = (float*)(ws + 5472256);                   // 512 KiB
  float* ctxb  = (float*)(ws + 5996544);                   // 64 KiB
  float* retrb = (float*)(ws + 6062080);                   // 64 KiB
  float* fusedb= (float*)(ws + 6127616);                   // 64 KiB
  float* t1b   = (float*)(ws + 6193152);                   // 32 KiB

  k_pack   <<<2304, 256, 0, stream>>>(w1, attw, w1p, wkvp);
  k_conv   <<<2048, 256, 0, stream>>>(x, w1p, cbv, bng, bnb, bnm, bnv, ppool, wavg, wmax);
  k_kv     <<<256,  256, 0, stream>>>(mb, wkvp, attb, kvb);
  k_qkattn <<<256,  256, 0, stream>>>(ppool, lw, lb, lng, lnb, kvb, attw, attb, ctxb, encb);
  k_outproj<<<256,  256, 0, stream>>>(ctxb, ow, obv, retrb);
  k_gate   <<<256,  256, 0, stream>>>(encb, retrb, gw, gb, fusedb);
  k_rec1   <<<128,  256, 0, stream>>>(fusedb, r1w, r1b, t1b);
  k_rec2   <<<128,  256, 0, stream>>>(t1b, r2w, r2b, swb);
  k_spconv <<<512,  256, 0, stream>>>(wavg, wmax, spw, sab);
  k_final  <<<2048, 256, 0, stream>>>(x, swb, sab, out);
}